// Round 7
// baseline (403.665 us; speedup 1.0000x reference)
//
#include <hip/hip_runtime.h>
#include <hip/hip_bf16.h>
#include <cstdint>
#include <cstddef>

#define AS1 __attribute__((address_space(1)))
#define AS3 __attribute__((address_space(3)))

typedef __bf16 bf16x8  __attribute__((ext_vector_type(8)));
typedef float  floatx4 __attribute__((ext_vector_type(4)));

__device__ __forceinline__ void load_lds16(const void* g, void* l) {
    __builtin_amdgcn_global_load_lds((AS1 void*)g, (AS3 void*)l, 16, 0, 0);
}

__device__ __forceinline__ float fexp2(float x) { return __builtin_amdgcn_exp2f(x); }
__device__ __forceinline__ float flog2(float x) { return __builtin_amdgcn_logf(x); }

#define LOG2E 1.4426950408889634f
#define LN2   0.6931471805599453f
#define C0K   2.3052328943245633f   /* 0.5*log(2pi) + log(4) */

__device__ __forceinline__ float logp2(float xv, float mu, float al) {
    float e = fexp2(-al * LOG2E);
    float z = (xv - mu) * e;
    return (-0.5f * z * z - al - C0K) * LOG2E;
}
__device__ __forceinline__ float lse4(float a0, float a1, float a2, float a3) {
    float mx = fmaxf(fmaxf(a0, a1), fmaxf(a2, a3));
    return mx + flog2(fexp2(a0 - mx) + fexp2(a1 - mx) +
                      fexp2(a2 - mx) + fexp2(a3 - mx));
}
__device__ __forceinline__ void lmm4(const float* Aa, const float* Bb, float* D) {
#pragma unroll
    for (int r = 0; r < 4; ++r)
#pragma unroll
        for (int c = 0; c < 4; ++c)
            D[r * 4 + c] = lse4(Aa[r * 4 + 0] + Bb[0 * 4 + c],
                                Aa[r * 4 + 1] + Bb[1 * 4 + c],
                                Aa[r * 4 + 2] + Bb[2 * 4 + c],
                                Aa[r * 4 + 3] + Bb[3 * 4 + c]);
}

// EXACT degree sort of the 2048 hidden features, deg(f) = f % 127.
__device__ __forceinline__ int resp_s(int p) {
    return p < 272 ? p / 17 : 16 + ((p - 272) >> 4);
}
__device__ __forceinline__ int invp_s(int p) {
    if (p < 272) { int d = p / 17; int r = p - d * 17;
                   return r < 16 ? d + r * 127 : 2032 + d; }
    int d = 16 + ((p - 272) >> 4); int j = (p - 272) & 15;
    return d + j * 127;
}
__device__ __forceinline__ int cnt_le(int D) {
    return D < 16 ? (D + 1) * 17 : 272 + ((D - 15) << 4);
}

// ---------------------------------------------------------------------------
// Prep: masks + fp32->bf16 + exact degree-sort, coalesced both sides via LDS.
// ---------------------------------------------------------------------------
__global__ __launch_bounds__(256)
void prep_all(const float* __restrict__ x,  const float* __restrict__ W0,
              const float* __restrict__ W1, const float* __restrict__ W2,
              const float* __restrict__ W3,
              __bf16* __restrict__ xb,  __bf16* __restrict__ w0m,
              __bf16* __restrict__ w1m, __bf16* __restrict__ w2m,
              __bf16* __restrict__ w3m)
{
    __shared__ float lds[2048];
    const int blk = blockIdx.x;
    const int tid = threadIdx.x;
    const int t8  = tid * 8;

    if (blk < 640) {                       // direct regions (x, W0)
        bf16x8 o;
        if (blk < 512) {                   // x copy
            size_t base = (size_t)blk * 2048 + t8;
            floatx4 a = *(const floatx4*)(x + base);
            floatx4 b = *(const floatx4*)(x + base + 4);
#pragma unroll
            for (int j = 0; j < 4; ++j) { o[j] = (__bf16)a[j]; o[4 + j] = (__bf16)b[j]; }
            *(bf16x8*)(xb + base) = o;
        } else {                           // W0: dst[p_n][c] = W0[invp(p_n)][c] * mask
            long idx = (long)(blk - 512) * 2048 + t8;
            int p_n = (int)(idx >> 7);
            int c   = (int)(idx & 127);
            int dg  = resp_s(p_n);
            const float* s = W0 + (long)invp_s(p_n) * 128 + c;
            floatx4 a = *(const floatx4*)s;
            floatx4 b = *(const floatx4*)(s + 4);
#pragma unroll
            for (int j = 0; j < 8; ++j) {
                float v = j < 4 ? a[j] : b[j - 4];
                o[j] = (__bf16)((dg >= c + j) ? v : 0.0f);
            }
            *(bf16x8*)(w0m + idx) = o;
        }
        return;
    }

    const float* srow; __bf16* drow; int deg_n; bool strict;
    if (blk < 2688) {
        int p_n = blk - 640;
        srow = W1 + (size_t)invp_s(p_n) * 2048; drow = w1m + (size_t)p_n * 2048;
        deg_n = resp_s(p_n); strict = false;
    } else if (blk < 4736) {
        int p_n = blk - 2688;
        srow = W2 + (size_t)invp_s(p_n) * 2048; drow = w2m + (size_t)p_n * 2048;
        deg_n = resp_s(p_n); strict = false;
    } else {
        int n = blk - 4736;
        srow = W3 + (size_t)n * 2048; drow = w3m + (size_t)n * 2048;
        deg_n = n >> 5; strict = true;
    }
    floatx4 a = *(const floatx4*)(srow + t8);
    floatx4 b = *(const floatx4*)(srow + t8 + 4);
    *(floatx4*)&lds[t8]     = a;
    *(floatx4*)&lds[t8 + 4] = b;
    __syncthreads();
    bf16x8 o;
#pragma unroll
    for (int j = 0; j < 8; ++j) {
        int p = t8 + j;
        float v = lds[invp_s(p)];
        int dg = resp_s(p);
        bool keep = strict ? (deg_n > dg) : (deg_n >= dg);
        o[j] = (__bf16)(keep ? v : 0.0f);
    }
    *(bf16x8*)(drow + t8) = o;
}

// ---------------------------------------------------------------------------
// gemm_k128: G0 specialist (K=128, 1-2 K-steps). LDS-free, barrier-free:
// inputs (xb 2MB, w0m 0.5MB) are L2-resident, so MFMA fragments load straight
// from global (16B/lane). Frag<->k mapping identical to gemm_bt's proven
// swizzle algebra: lane(fr,ks) holds A[row=fr][k = kt + (half?32:0) + ks*8].
// No staging prologue -> cost approaches the compulsory h1 write.
// ---------------------------------------------------------------------------
template <bool PERMBIAS>
__global__ __launch_bounds__(256, 8)
void gemm_k128(const __bf16* __restrict__ A, const __bf16* __restrict__ Bw,
               const float* __restrict__ bias, __bf16* __restrict__ Cout,
               int N)
{
    const int K = 128;
    const int tid  = threadIdx.x;
    const int wave = tid >> 6;
    const int lane = tid & 63;
    const int bm = blockIdx.x;
    const int bn = (gridDim.y - 1) - blockIdx.y;     // LPT order
    const int wm = wave >> 1, wn = wave & 1;
    const int fr = lane & 15, ks = lane >> 4;

    const __bf16* arow[4];
    const __bf16* brow[4];
#pragma unroll
    for (int i = 0; i < 4; ++i) {
        arow[i] = A  + (size_t)(bm * 128 + wm * 64 + i * 16 + fr) * K + ks * 8;
        brow[i] = Bw + (size_t)(bn * 128 + wn * 64 + i * 16 + fr) * K + ks * 8;
    }

    floatx4 acc[4][4];
    const floatx4 vzero = {0.f, 0.f, 0.f, 0.f};
#pragma unroll
    for (int mi = 0; mi < 4; ++mi)
#pragma unroll
        for (int ni = 0; ni < 4; ++ni) acc[mi][ni] = vzero;

    int limit = (resp_s(bn * 128 + 127) + 64) >> 6;  // 1 or 2
    if (limit > 2) limit = 2;

    for (int it = 0; it < limit; ++it) {
        const int kt = it << 6;
        bf16x8 af[4], bf[4];
#pragma unroll
        for (int i = 0; i < 4; ++i) af[i] = *(const bf16x8*)(arow[i] + kt);
#pragma unroll
        for (int i = 0; i < 4; ++i) bf[i] = *(const bf16x8*)(brow[i] + kt);
#pragma unroll
        for (int mi = 0; mi < 4; ++mi)
#pragma unroll
            for (int ni = 0; ni < 4; ++ni)
                acc[mi][ni] = __builtin_amdgcn_mfma_f32_16x16x32_bf16(
                    af[mi], bf[ni], acc[mi][ni], 0, 0, 0);
#pragma unroll
        for (int i = 0; i < 4; ++i) af[i] = *(const bf16x8*)(arow[i] + kt + 32);
#pragma unroll
        for (int i = 0; i < 4; ++i) bf[i] = *(const bf16x8*)(brow[i] + kt + 32);
#pragma unroll
        for (int mi = 0; mi < 4; ++mi)
#pragma unroll
            for (int ni = 0; ni < 4; ++ni)
                acc[mi][ni] = __builtin_amdgcn_mfma_f32_16x16x32_bf16(
                    af[mi], bf[ni], acc[mi][ni], 0, 0, 0);
    }

    const int cn  = lane & 15;
    const int cr4 = (lane >> 4) * 4;
#pragma unroll
    for (int ni = 0; ni < 4; ++ni) {
        int col = bn * 128 + wn * 64 + ni * 16 + cn;
        float bv = bias[PERMBIAS ? invp_s(col) : col];
#pragma unroll
        for (int mi = 0; mi < 4; ++mi) {
            int row0 = bm * 128 + wm * 64 + mi * 16 + cr4;
#pragma unroll
            for (int q = 0; q < 4; ++q) {
                float v = fmaxf(acc[mi][ni][q] + bv, 0.f);   // RELU
                Cout[(size_t)(row0 + q) * N + col] = (__bf16)v;
            }
        }
    }
}

// ---------------------------------------------------------------------------
// bf16 MFMA GEMM, BK=64, 16x16x32 MFMA 4x4/wave (R9-proven K-loop).
// 128x128 tile, 4 blocks/CU. Used for GEMM3 (best measured: 69us with the
// step-contiguous TLAYOUT; every deeper-pipeline or swizzle variant
// regressed -- see rounds 1-3).
// TLAYOUT: th[b>>6][i][b&63][w] with f = i*32+w so the chain kernel reads
// each step's 32 params as contiguous 64B.
// ---------------------------------------------------------------------------
template <bool RELU, bool OBF16, bool TLAYOUT, bool PERMBIAS, int LMODE>
__global__ __launch_bounds__(256, 4)
void gemm_bt(const __bf16* __restrict__ A, const __bf16* __restrict__ Bw,
             const float* __restrict__ bias, void* __restrict__ Cout,
             int N, int K)
{
    __shared__ __align__(16) __bf16 lsA[128 * 64];   // 16 KB
    __shared__ __align__(16) __bf16 lsB[128 * 64];   // 16 KB
    const int tid  = threadIdx.x;
    const int wave = tid >> 6;
    const int lane = tid & 63;
    const int bm = blockIdx.x;
    const int bn = (gridDim.y - 1) - blockIdx.y;     // LPT order
    const int wm = wave >> 1, wn = wave & 1;

    const int r8 = lane >> 3;
    const int cb = (lane & 7) ^ r8;
    const __bf16* gsrc[8];
    __bf16* ldst[8];
#pragma unroll
    for (int t = 0; t < 8; ++t) {
        int j = wave * 8 + t;
        if (j < 16) {
            int row = bm * 128 + j * 8 + r8;
            gsrc[t] = A + (size_t)row * K + cb * 8;
            ldst[t] = lsA + j * 512;
        } else {
            int jj = j - 16;
            int row = bn * 128 + jj * 8 + r8;
            gsrc[t] = Bw + (size_t)row * K + cb * 8;
            ldst[t] = lsB + jj * 512;
        }
    }

    const int fr  = lane & 15;
    const int ks  = lane >> 4;
    const int sx  = fr & 7;
    const int sl0 = ((ks)     ^ sx) * 8;
    const int sl1 = ((4 + ks) ^ sx) * 8;
    const __bf16* arow[4];
    const __bf16* brow[4];
#pragma unroll
    for (int i = 0; i < 4; ++i) {
        arow[i] = lsA + (wm * 64 + i * 16 + fr) * 64;
        brow[i] = lsB + (wn * 64 + i * 16 + fr) * 64;
    }

    floatx4 acc[4][4];
    const floatx4 vzero = {0.f, 0.f, 0.f, 0.f};
#pragma unroll
    for (int mi = 0; mi < 4; ++mi)
#pragma unroll
        for (int ni = 0; ni < 4; ++ni) acc[mi][ni] = vzero;

    const int nk = K >> 6;
    int limit;
    if (LMODE == 0)      limit = (cnt_le(resp_s(bn * 128 + 127)) + 63) >> 6;
    else if (LMODE == 1) { int D = 4 * bn + 2; if (D > 126) D = 126;
                           limit = (cnt_le(D) + 63) >> 6; }
    else                 limit = (resp_s(bn * 128 + 127) + 64) >> 6;
    if (limit > nk) limit = nk;

    for (int it = 0; it < limit; ++it) {
        const int kt = it << 6;
        __syncthreads();
#pragma unroll
        for (int t = 0; t < 8; ++t)
            load_lds16((const void*)(gsrc[t] + kt), (void*)ldst[t]);
        __syncthreads();
        bf16x8 af[4], bf[4];
#pragma unroll
        for (int i = 0; i < 4; ++i) af[i] = *(const bf16x8*)(arow[i] + sl0);
#pragma unroll
        for (int i = 0; i < 4; ++i) bf[i] = *(const bf16x8*)(brow[i] + sl0);
#pragma unroll
        for (int mi = 0; mi < 4; ++mi)
#pragma unroll
            for (int ni = 0; ni < 4; ++ni)
                acc[mi][ni] = __builtin_amdgcn_mfma_f32_16x16x32_bf16(
                    af[mi], bf[ni], acc[mi][ni], 0, 0, 0);
#pragma unroll
        for (int i = 0; i < 4; ++i) af[i] = *(const bf16x8*)(arow[i] + sl1);
#pragma unroll
        for (int i = 0; i < 4; ++i) bf[i] = *(const bf16x8*)(brow[i] + sl1);
#pragma unroll
        for (int mi = 0; mi < 4; ++mi)
#pragma unroll
            for (int ni = 0; ni < 4; ++ni)
                acc[mi][ni] = __builtin_amdgcn_mfma_f32_16x16x32_bf16(
                    af[mi], bf[ni], acc[mi][ni], 0, 0, 0);
    }

    const int cn  = lane & 15;
    const int cr4 = (lane >> 4) * 4;
#pragma unroll
    for (int ni = 0; ni < 4; ++ni) {
        int col = bn * 128 + wn * 64 + ni * 16 + cn;
        float bv = bias[PERMBIAS ? invp_s(col) : col];
#pragma unroll
        for (int mi = 0; mi < 4; ++mi) {
            int row0 = bm * 128 + wm * 64 + mi * 16 + cr4;
#pragma unroll
            for (int q = 0; q < 4; ++q) {
                float v = acc[mi][ni][q] + bv;
                if (RELU) v = fmaxf(v, 0.f);
                if (TLAYOUT) {
                    // b = row0+q: g = b>>6 = bm*2+wm; bq = b&63 = mi*16+cr4+q
                    // f = col: i = col>>5, w = col&31
                    size_t addr = (size_t)(bm * 2 + wm) * ((size_t)N * 64)
                                + (size_t)(col >> 5) * 2048
                                + (size_t)(mi * 16 + cr4 + q) * 32 + (col & 31);
                    ((__bf16*)Cout)[addr] = (__bf16)v;
                } else if (OBF16) {
                    ((__bf16*)Cout)[(size_t)(row0 + q) * N + col] = (__bf16)v;
                } else {
                    ((float*)Cout)[(size_t)(row0 + q) * N + col] = v;
                }
            }
        }
    }
}

#define CFENCE() asm volatile("" ::: "memory")
#define BARX()  do { CFENCE(); __builtin_amdgcn_s_barrier(); CFENCE(); } while (0)
#define WVM2()  asm volatile("s_waitcnt vmcnt(2)" ::: "memory")
#define WVM0()  asm volatile("s_waitcnt vmcnt(0)" ::: "memory")
#define WLGK()  asm volatile("s_waitcnt lgkmcnt(0)" ::: "memory")

// ---------------------------------------------------------------------------
// gemm8p: 256x128 tile, 4-phase counted-vmcnt. Used for GEMM1/2 only
// (measured -22us combined vs gemm_bt in round 1; regressed G3 in round 1).
// No XCD swizzle (round 3: swizzle thrashes L3 on this L3-resident problem).
// ---------------------------------------------------------------------------
template <bool RELU, bool OBF16, bool TLAYOUT, bool PERMBIAS, int LMODE>
__global__ __launch_bounds__(512)
void gemm8p(const __bf16* __restrict__ A, const __bf16* __restrict__ Bw,
            const float* __restrict__ bias, void* __restrict__ Cout,
            int N, int K)
{
    __shared__ __align__(16) __bf16 ls[2 * 24576];
    const int tid  = threadIdx.x;
    const int wave = tid >> 6;
    const int lane = tid & 63;
    const int bm = blockIdx.x;
    const int bn = (gridDim.y - 1) - blockIdx.y;   // LPT order
    const int wm = wave >> 1, wn = wave & 1;       // 4M x 2N

    const int l8 = lane >> 3;
    const int cb = (lane & 7) ^ l8;
    const __bf16* gA[2][2];  int dA[2][2];
    const __bf16* gB[2];     int dB[2];
#pragma unroll
    for (int h = 0; h < 2; ++h)
#pragma unroll
        for (int s = 0; s < 2; ++s) {
            int rt = h * 128 + wave * 16 + s * 8;
            gA[h][s] = A + (size_t)(bm * 256 + rt + l8) * K + cb * 8;
            dA[h][s] = rt * 64;
        }
#pragma unroll
    for (int s = 0; s < 2; ++s) {
        int rt = wave * 16 + s * 8;
        gB[s] = Bw + (size_t)(bn * 128 + rt + l8) * K + cb * 8;
        dB[s] = 16384 + rt * 64;
    }

#define STG_A(buf, kt) do { \
    load_lds16((const void*)(gA[0][0] + (kt)), (void*)(ls + (buf)*24576 + dA[0][0])); \
    load_lds16((const void*)(gA[0][1] + (kt)), (void*)(ls + (buf)*24576 + dA[0][1])); \
    load_lds16((const void*)(gA[1][0] + (kt)), (void*)(ls + (buf)*24576 + dA[1][0])); \
    load_lds16((const void*)(gA[1][1] + (kt)), (void*)(ls + (buf)*24576 + dA[1][1])); } while (0)
#define STG_B(buf, kt) do { \
    load_lds16((const void*)(gB[0] + (kt)), (void*)(ls + (buf)*24576 + dB[0])); \
    load_lds16((const void*)(gB[1] + (kt)), (void*)(ls + (buf)*24576 + dB[1])); } while (0)

    const int fr  = lane & 15;
    const int ks  = lane >> 4;
    const int sx  = fr & 7;
    const int sl0 = ((ks)     ^ sx) * 8;
    const int sl1 = ((4 + ks) ^ sx) * 8;
    int aoff[4], boff[4];
#pragma unroll
    for (int i = 0; i < 4; ++i) {
        aoff[i] = (wm * 64 + i * 16 + fr) * 64;
        boff[i] = 16384 + (wn * 64 + i * 16 + fr) * 64;
    }

    floatx4 acc[4][4];
    const floatx4 vzero = {0.f, 0.f, 0.f, 0.f};
#pragma unroll
    for (int mi = 0; mi < 4; ++mi)
#pragma unroll
        for (int ni = 0; ni < 4; ++ni) acc[mi][ni] = vzero;

    bf16x8 bfr[4][2], afr[2][2];

#define DSRD_B(buf) do { \
    _Pragma("unroll") \
    for (int ni = 0; ni < 4; ++ni) { \
        bfr[ni][0] = *(const bf16x8*)(ls + (buf)*24576 + boff[ni] + sl0); \
        bfr[ni][1] = *(const bf16x8*)(ls + (buf)*24576 + boff[ni] + sl1); } } while (0)
#define DSRD_A(buf, q) do { \
    _Pragma("unroll") \
    for (int j = 0; j < 2; ++j) { \
        afr[j][0] = *(const bf16x8*)(ls + (buf)*24576 + aoff[2*(q)+j] + sl0); \
        afr[j][1] = *(const bf16x8*)(ls + (buf)*24576 + aoff[2*(q)+j] + sl1); } } while (0)
#define MFMA16(q) do { \
    __builtin_amdgcn_s_setprio(1); \
    _Pragma("unroll") \
    for (int j = 0; j < 2; ++j) \
    _Pragma("unroll") \
    for (int ni = 0; ni < 4; ++ni) { \
        acc[2*(q)+j][ni] = __builtin_amdgcn_mfma_f32_16x16x32_bf16( \
            afr[j][0], bfr[ni][0], acc[2*(q)+j][ni], 0, 0, 0); \
        acc[2*(q)+j][ni] = __builtin_amdgcn_mfma_f32_16x16x32_bf16( \
            afr[j][1], bfr[ni][1], acc[2*(q)+j][ni], 0, 0, 0); } \
    __builtin_amdgcn_s_setprio(0); } while (0)

    const int nk = K >> 6;
    int limit;
    if (LMODE == 0)      limit = (cnt_le(resp_s(bn * 128 + 127)) + 63) >> 6;
    else if (LMODE == 1) { int D = 4 * bn + 2; if (D > 126) D = 126;
                           limit = (cnt_le(D) + 63) >> 6; }
    else                 limit = (resp_s(bn * 128 + 127) + 64) >> 6;
    if (limit > nk) limit = nk;
    const int NT = limit;

    STG_B(0, 0);
    STG_A(0, 0);
    if (NT > 1) { STG_B(1, 64); WVM2(); } else { WVM0(); }
    BARX();

    for (int t = 0; ; t += 2) {
        const int kt1 = (t + 1) << 6, kt2 = (t + 2) << 6, kt3 = (t + 3) << 6;
        const bool has1 = t + 1 < NT, has2 = t + 2 < NT, has3 = t + 3 < NT;

        DSRD_B(0);
        DSRD_A(0, 0);
        if (has1) STG_A(1, kt1);
        BARX(); WLGK();
        MFMA16(0);
        BARX();

        DSRD_A(0, 1);
        if (has2) STG_B(0, kt2);
        BARX(); WLGK();
        MFMA16(1);
        if (!has1) break;
        if (has2) WVM2(); else WVM0();
        BARX();

        DSRD_B(1);
        DSRD_A(1, 0);
        if (has2) STG_A(0, kt2);
        BARX(); WLGK();
        MFMA16(0);
        BARX();

        DSRD_A(1, 1);
        if (has3) STG_B(1, kt3);
        BARX(); WLGK();
        MFMA16(1);
        if (!has2) break;
        if (has3) WVM2(); else WVM0();
        BARX();
    }

    const int cn  = lane & 15;
    const int cr4 = (lane >> 4) * 4;
#pragma unroll
    for (int ni = 0; ni < 4; ++ni) {
        int col = bn * 128 + wn * 64 + ni * 16 + cn;
        float bv = bias[PERMBIAS ? invp_s(col) : col];
#pragma unroll
        for (int mi = 0; mi < 4; ++mi) {
            int row0 = bm * 256 + wm * 64 + mi * 16 + cr4;
#pragma unroll
            for (int q = 0; q < 4; ++q) {
                float v = acc[mi][ni][q] + bv;
                if (RELU) v = fmaxf(v, 0.f);
                if (TLAYOUT) {
                    size_t addr = (size_t)(bm * 4 + wm) * ((size_t)N * 64)
                                + (size_t)(col >> 5) * 2048
                                + (size_t)(mi * 16 + cr4 + q) * 32 + (col & 31);
                    ((__bf16*)Cout)[addr] = (__bf16)v;
                } else if (OBF16) {
                    ((__bf16*)Cout)[(size_t)(row0 + q) * N + col] = (__bf16)v;
                } else {
                    ((float*)Cout)[(size_t)(row0 + q) * N + col] = v;
                }
            }
        }
    }
#undef STG_A
#undef STG_B
#undef DSRD_B
#undef DSRD_A
#undef MFMA16
}

// ---------------------------------------------------------------------------
// Fused log-semiring chain: 126 steps = 18 segs x 7 (was 14x9): 576 thr =
// 9 waves/CU (+28% TLP), serial depth 7 (-22%). Segments in registers ->
// LDS -> pair-tree fold + boundaries. theta layout th[b>>6][i][b&63][32]:
// step params contiguous 64B -> 4 aligned bf16x8 loads/step.
// ---------------------------------------------------------------------------
__global__ __launch_bounds__(576)
void chain_all(const __bf16* __restrict__ th2,  // [128][128][64][32] bf16
               const float* __restrict__ x,     // [8192,128]
               float* __restrict__ out)         // [8192]
{
    __shared__ float xs[32 * 129];               // 16.5 KB (pad 129: no conflicts)
    __shared__ float Pl[32 * 306];               // 39.2 KB: [bl][s*17 + e], 18 segs
    const int tid = threadIdx.x;
    const int blk = blockIdx.x;                  // 0..255

    for (int idx = tid; idx < 4096; idx += 576) {
        int bl = idx >> 7, i = idx & 127;
        xs[bl * 129 + i] = x[(size_t)blk * 4096 + idx];
    }
    __syncthreads();

    const int s  = tid >> 5;                     // 0..17
    const int bl = tid & 31;
    const int b64 = (blk & 1) * 32 + bl;
    const __bf16* tb = th2 + (size_t)(blk >> 1) * 262144 + (size_t)b64 * 32;

    {   // segment product: 7 steps from i0
        const int i0 = 1 + s * 7;
        const __bf16* tp = tb + (size_t)i0 * 2048;
        float M[4][4];
#pragma unroll
        for (int r = 0; r < 4; ++r)
#pragma unroll
            for (int c = 0; c < 4; ++c) M[r][c] = (r == c) ? 0.f : -1e30f;

        for (int ii = 0; ii < 7; ++ii) {
            bf16x8 v0 = *(const bf16x8*)(tp);
            bf16x8 v1 = *(const bf16x8*)(tp + 8);
            bf16x8 v2 = *(const bf16x8*)(tp + 16);
            bf16x8 v3 = *(const bf16x8*)(tp + 24);
            float mu[16], al[16];
#pragma unroll
            for (int j = 0; j < 8; ++j) {
                mu[j] = (float)v0[j]; mu[8 + j] = (float)v1[j];
                al[j] = (float)v2[j]; al[8 + j] = (float)v3[j];
            }
            float xv = xs[bl * 129 + i0 + ii];
            tp += 2048;                          // next step
            float lp[16];
#pragma unroll
            for (int j = 0; j < 16; ++j) lp[j] = logp2(xv, mu[j], al[j]);
            float Mn[4][4];
#pragma unroll
            for (int r = 0; r < 4; ++r)
#pragma unroll
                for (int c = 0; c < 4; ++c)
                    Mn[r][c] = lse4(M[r][0] + lp[0 + c], M[r][1] + lp[4 + c],
                                    M[r][2] + lp[8 + c], M[r][3] + lp[12 + c]);
#pragma unroll
            for (int r = 0; r < 4; ++r)
#pragma unroll
                for (int c = 0; c < 4; ++c) M[r][c] = Mn[r][c];
        }
        float* pb = Pl + bl * 306 + s * 17;
#pragma unroll
        for (int r = 0; r < 4; ++r)
#pragma unroll
            for (int c = 0; c < 4; ++c) pb[r * 4 + c] = M[r][c];
    }
    __syncthreads();

    // fold level 1: 9 pair-products per batch (threads 0..287)
    float Q[16];
    if (tid < 288) {
        const float* base = Pl + bl * 306;
        lmm4(base + (2 * s) * 17, base + (2 * s + 1) * 17, Q);
    }
    __syncthreads();
    if (tid < 288) {
        float* dst = Pl + bl * 306 + s * 17;
#pragma unroll
        for (int e = 0; e < 16; ++e) dst[e] = Q[e];
    }
    __syncthreads();

    // fold level 2 + boundaries: one thread per batch (9 slots sequential)
    if (tid < 32) {
        const float* base = Pl + tid * 306;
        float M[16], T[16];
#pragma unroll
        for (int e = 0; e < 16; ++e) M[e] = base[e];
#pragma unroll
        for (int j = 1; j < 9; ++j) {
            lmm4(M, base + j * 17, T);
#pragma unroll
            for (int e = 0; e < 16; ++e) M[e] = T[e];
        }
        const int bb64 = (blk & 1) * 32 + tid;
        const __bf16* tbb = th2 + (size_t)(blk >> 1) * 262144 + (size_t)bb64 * 32;
        float x0 = xs[tid * 129 + 0];
        float xl = xs[tid * 129 + 127];
        float last[4], t4[4], f4[4];
        // last step i=127: mu at w=c*4 (a_row=c, a_col=0), al at 16+c*4
#pragma unroll
        for (int c = 0; c < 4; ++c)
            last[c] = logp2(xl, (float)tbb[(size_t)127 * 2048 + c * 4],
                                (float)tbb[(size_t)127 * 2048 + 16 + c * 4]);
#pragma unroll
        for (int r = 0; r < 4; ++r)
            t4[r] = lse4(M[r * 4 + 0] + last[0], M[r * 4 + 1] + last[1],
                         M[r * 4 + 2] + last[2], M[r * 4 + 3] + last[3]);
        // first step i=0: mu at w=r (a_row=0, a_col=r), al at 16+r
#pragma unroll
        for (int r = 0; r < 4; ++r)
            f4[r] = logp2(x0, (float)tbb[r], (float)tbb[16 + r]);
        out[blk * 32 + tid] = LN2 * lse4(f4[0] + t4[0], f4[1] + t4[1],
                                         f4[2] + t4[2], f4[3] + t4[3]);
    }
}

// ---------------------------------------------------------------------------
extern "C" void kernel_launch(void* const* d_in, const int* in_sizes, int n_in,
                              void* d_out, int out_size, void* d_ws, size_t ws_size,
                              hipStream_t stream)
{
    (void)in_sizes; (void)n_in; (void)out_size; (void)ws_size;
    const float* x  = (const float*)d_in[0];
    const float* W0 = (const float*)d_in[1];
    const float* b0 = (const float*)d_in[2];
    const float* W1 = (const float*)d_in[3];
    const float* b1 = (const float*)d_in[4];
    const float* W2 = (const float*)d_in[5];
    const float* b2 = (const float*)d_in[6];
    const float* W3 = (const float*)d_in[7];
    const float* b3 = (const float*)d_in[8];

    // Compact arena (112 MB): th overlays regions dead before GEMM3.
    char* ws = (char*)d_ws;
    const size_t MB = 1024 * 1024;
    __bf16* h2  = (__bf16*)(ws + 0);          // 32 MB: g1 out, g2 in; dead after g2
    __bf16* xb  = (__bf16*)(ws + 32 * MB);    // 2 MB:  prep -> g0
    __bf16* w0m = (__bf16*)(ws + 34 * MB);    // 0.5MB: prep -> g0
    __bf16* w1m = (__bf16*)(ws + 35 * MB);    // 8 MB:  prep -> g1
    __bf16* w2m = (__bf16*)(ws + 43 * MB);    // 8 MB:  prep -> g2
    __bf16* th  = (__bf16*)(ws + 0);          // 64 MB: g3 out (overlays the above)
    __bf16* w3m = (__bf16*)(ws + 64 * MB);    // 16 MB: prep -> g3 (not overlaid)
    __bf16* h1  = (__bf16*)(ws + 80 * MB);    // 32 MB: g0 out; g2 writes h3=h1; g3 in
    __bf16* h3  = h1;

    prep_all<<<8832, 256, 0, stream>>>(x, W0, W1, W2, W3, xb, w0m, w1m, w2m, w3m);

    // GEMM0: sorted N, natural K=128 — LDS-free direct-load specialist
    gemm_k128<true><<<dim3(64, 16), 256, 0, stream>>>(xb, w0m, b0, h1, 2048);
    // GEMM1/2: sorted N, sorted K (LMODE 0) — 256x128 4-phase (round-1 best)
    gemm8p<true, true, false, true, 0><<<dim3(32, 16), 512, 0, stream>>>(
        h1, w1m, b1, h2, 2048, 2048);
    gemm8p<true, true, false, true, 0><<<dim3(32, 16), 512, 0, stream>>>(
        h2, w2m, b2, h3, 2048, 2048);
    // GEMM3: natural N, sorted K (LMODE 1) — 128^2 kernel (round-0 best),
    // theta stored step-contiguous for chain
    gemm_bt<false, false, true, false, 1><<<dim3(64, 32), 256, 0, stream>>>(
        h3, w3m, b3, th, 4096, 2048);

    // fused segment chain + fold (single dispatch)
    chain_all<<<256, 576, 0, stream>>>(th, x, (float*)d_out);
}

// Round 8
// 314.417 us; speedup vs baseline: 1.2839x; 1.2839x over previous
//
#include <hip/hip_runtime.h>
#include <hip/hip_bf16.h>
#include <cstdint>
#include <cstddef>

#define AS1 __attribute__((address_space(1)))
#define AS3 __attribute__((address_space(3)))

typedef __bf16 bf16x8  __attribute__((ext_vector_type(8)));
typedef float  floatx4 __attribute__((ext_vector_type(4)));

__device__ __forceinline__ void load_lds16(const void* g, void* l) {
    __builtin_amdgcn_global_load_lds((AS1 void*)g, (AS3 void*)l, 16, 0, 0);
}

__device__ __forceinline__ float fexp2(float x) { return __builtin_amdgcn_exp2f(x); }
__device__ __forceinline__ float flog2(float x) { return __builtin_amdgcn_logf(x); }

#define LOG2E 1.4426950408889634f
#define LN2   0.6931471805599453f
#define C0K   2.3052328943245633f   /* 0.5*log(2pi) + log(4) */

__device__ __forceinline__ float logp2(float xv, float mu, float al) {
    float e = fexp2(-al * LOG2E);
    float z = (xv - mu) * e;
    return (-0.5f * z * z - al - C0K) * LOG2E;
}
__device__ __forceinline__ float lse4(float a0, float a1, float a2, float a3) {
    float mx = fmaxf(fmaxf(a0, a1), fmaxf(a2, a3));
    return mx + flog2(fexp2(a0 - mx) + fexp2(a1 - mx) +
                      fexp2(a2 - mx) + fexp2(a3 - mx));
}
__device__ __forceinline__ void lmm4(const float* Aa, const float* Bb, float* D) {
#pragma unroll
    for (int r = 0; r < 4; ++r)
#pragma unroll
        for (int c = 0; c < 4; ++c)
            D[r * 4 + c] = lse4(Aa[r * 4 + 0] + Bb[0 * 4 + c],
                                Aa[r * 4 + 1] + Bb[1 * 4 + c],
                                Aa[r * 4 + 2] + Bb[2 * 4 + c],
                                Aa[r * 4 + 3] + Bb[3 * 4 + c]);
}

// EXACT degree sort of the 2048 hidden features, deg(f) = f % 127.
__device__ __forceinline__ int resp_s(int p) {
    return p < 272 ? p / 17 : 16 + ((p - 272) >> 4);
}
__device__ __forceinline__ int invp_s(int p) {
    if (p < 272) { int d = p / 17; int r = p - d * 17;
                   return r < 16 ? d + r * 127 : 2032 + d; }
    int d = 16 + ((p - 272) >> 4); int j = (p - 272) & 15;
    return d + j * 127;
}
__device__ __forceinline__ int cnt_le(int D) {
    return D < 16 ? (D + 1) * 17 : 272 + ((D - 15) << 4);
}

// ---------------------------------------------------------------------------
// Prep: masks + fp32->bf16 + exact degree-sort, coalesced both sides via LDS.
// ---------------------------------------------------------------------------
__global__ __launch_bounds__(256)
void prep_all(const float* __restrict__ x,  const float* __restrict__ W0,
              const float* __restrict__ W1, const float* __restrict__ W2,
              const float* __restrict__ W3,
              __bf16* __restrict__ xb,  __bf16* __restrict__ w0m,
              __bf16* __restrict__ w1m, __bf16* __restrict__ w2m,
              __bf16* __restrict__ w3m)
{
    __shared__ float lds[2048];
    const int blk = blockIdx.x;
    const int tid = threadIdx.x;
    const int t8  = tid * 8;

    if (blk < 640) {                       // direct regions (x, W0)
        bf16x8 o;
        if (blk < 512) {                   // x copy
            size_t base = (size_t)blk * 2048 + t8;
            floatx4 a = *(const floatx4*)(x + base);
            floatx4 b = *(const floatx4*)(x + base + 4);
#pragma unroll
            for (int j = 0; j < 4; ++j) { o[j] = (__bf16)a[j]; o[4 + j] = (__bf16)b[j]; }
            *(bf16x8*)(xb + base) = o;
        } else {                           // W0: dst[p_n][c] = W0[invp(p_n)][c] * mask
            long idx = (long)(blk - 512) * 2048 + t8;
            int p_n = (int)(idx >> 7);
            int c   = (int)(idx & 127);
            int dg  = resp_s(p_n);
            const float* s = W0 + (long)invp_s(p_n) * 128 + c;
            floatx4 a = *(const floatx4*)s;
            floatx4 b = *(const floatx4*)(s + 4);
#pragma unroll
            for (int j = 0; j < 8; ++j) {
                float v = j < 4 ? a[j] : b[j - 4];
                o[j] = (__bf16)((dg >= c + j) ? v : 0.0f);
            }
            *(bf16x8*)(w0m + idx) = o;
        }
        return;
    }

    const float* srow; __bf16* drow; int deg_n; bool strict;
    if (blk < 2688) {
        int p_n = blk - 640;
        srow = W1 + (size_t)invp_s(p_n) * 2048; drow = w1m + (size_t)p_n * 2048;
        deg_n = resp_s(p_n); strict = false;
    } else if (blk < 4736) {
        int p_n = blk - 2688;
        srow = W2 + (size_t)invp_s(p_n) * 2048; drow = w2m + (size_t)p_n * 2048;
        deg_n = resp_s(p_n); strict = false;
    } else {
        int n = blk - 4736;
        srow = W3 + (size_t)n * 2048; drow = w3m + (size_t)n * 2048;
        deg_n = n >> 5; strict = true;
    }
    floatx4 a = *(const floatx4*)(srow + t8);
    floatx4 b = *(const floatx4*)(srow + t8 + 4);
    *(floatx4*)&lds[t8]     = a;
    *(floatx4*)&lds[t8 + 4] = b;
    __syncthreads();
    bf16x8 o;
#pragma unroll
    for (int j = 0; j < 8; ++j) {
        int p = t8 + j;
        float v = lds[invp_s(p)];
        int dg = resp_s(p);
        bool keep = strict ? (deg_n > dg) : (deg_n >= dg);
        o[j] = (__bf16)(keep ? v : 0.0f);
    }
    *(bf16x8*)(drow + t8) = o;
}

// ---------------------------------------------------------------------------
// bf16 MFMA GEMM, BK=64, 16x16x32 MFMA 4x4/wave (R9-proven K-loop).
// 128x128 tile, 4 blocks/CU. Used for GEMM0 and GEMM3.
// NOTE (r7 lesson): G0 must keep this LDS-staged form. The LDS-free
// direct-load variant (gemm_k128) flooded L2 with partial-line bf16 stores:
// WRITE_SIZE 290MB (9x h1), FETCH 124MB (RMW), 104us. The staging loop is
// the traffic governor, not overhead.
// TLAYOUT: th[b>>6][i][b&63][w] with f = i*32+w so the chain kernel reads
// each step's 32 params as contiguous 64B.
// ---------------------------------------------------------------------------
template <bool RELU, bool OBF16, bool TLAYOUT, bool PERMBIAS, int LMODE>
__global__ __launch_bounds__(256, 4)
void gemm_bt(const __bf16* __restrict__ A, const __bf16* __restrict__ Bw,
             const float* __restrict__ bias, void* __restrict__ Cout,
             int N, int K)
{
    __shared__ __align__(16) __bf16 lsA[128 * 64];   // 16 KB
    __shared__ __align__(16) __bf16 lsB[128 * 64];   // 16 KB
    const int tid  = threadIdx.x;
    const int wave = tid >> 6;
    const int lane = tid & 63;
    const int bm = blockIdx.x;
    const int bn = (gridDim.y - 1) - blockIdx.y;     // LPT order
    const int wm = wave >> 1, wn = wave & 1;

    const int r8 = lane >> 3;
    const int cb = (lane & 7) ^ r8;
    const __bf16* gsrc[8];
    __bf16* ldst[8];
#pragma unroll
    for (int t = 0; t < 8; ++t) {
        int j = wave * 8 + t;
        if (j < 16) {
            int row = bm * 128 + j * 8 + r8;
            gsrc[t] = A + (size_t)row * K + cb * 8;
            ldst[t] = lsA + j * 512;
        } else {
            int jj = j - 16;
            int row = bn * 128 + jj * 8 + r8;
            gsrc[t] = Bw + (size_t)row * K + cb * 8;
            ldst[t] = lsB + jj * 512;
        }
    }

    const int fr  = lane & 15;
    const int ks  = lane >> 4;
    const int sx  = fr & 7;
    const int sl0 = ((ks)     ^ sx) * 8;
    const int sl1 = ((4 + ks) ^ sx) * 8;
    const __bf16* arow[4];
    const __bf16* brow[4];
#pragma unroll
    for (int i = 0; i < 4; ++i) {
        arow[i] = lsA + (wm * 64 + i * 16 + fr) * 64;
        brow[i] = lsB + (wn * 64 + i * 16 + fr) * 64;
    }

    floatx4 acc[4][4];
    const floatx4 vzero = {0.f, 0.f, 0.f, 0.f};
#pragma unroll
    for (int mi = 0; mi < 4; ++mi)
#pragma unroll
        for (int ni = 0; ni < 4; ++ni) acc[mi][ni] = vzero;

    const int nk = K >> 6;
    int limit;
    if (LMODE == 0)      limit = (cnt_le(resp_s(bn * 128 + 127)) + 63) >> 6;
    else if (LMODE == 1) { int D = 4 * bn + 2; if (D > 126) D = 126;
                           limit = (cnt_le(D) + 63) >> 6; }
    else                 limit = (resp_s(bn * 128 + 127) + 64) >> 6;
    if (limit > nk) limit = nk;

    for (int it = 0; it < limit; ++it) {
        const int kt = it << 6;
        __syncthreads();
#pragma unroll
        for (int t = 0; t < 8; ++t)
            load_lds16((const void*)(gsrc[t] + kt), (void*)ldst[t]);
        __syncthreads();
        bf16x8 af[4], bf[4];
#pragma unroll
        for (int i = 0; i < 4; ++i) af[i] = *(const bf16x8*)(arow[i] + sl0);
#pragma unroll
        for (int i = 0; i < 4; ++i) bf[i] = *(const bf16x8*)(brow[i] + sl0);
#pragma unroll
        for (int mi = 0; mi < 4; ++mi)
#pragma unroll
            for (int ni = 0; ni < 4; ++ni)
                acc[mi][ni] = __builtin_amdgcn_mfma_f32_16x16x32_bf16(
                    af[mi], bf[ni], acc[mi][ni], 0, 0, 0);
#pragma unroll
        for (int i = 0; i < 4; ++i) af[i] = *(const bf16x8*)(arow[i] + sl1);
#pragma unroll
        for (int i = 0; i < 4; ++i) bf[i] = *(const bf16x8*)(brow[i] + sl1);
#pragma unroll
        for (int mi = 0; mi < 4; ++mi)
#pragma unroll
            for (int ni = 0; ni < 4; ++ni)
                acc[mi][ni] = __builtin_amdgcn_mfma_f32_16x16x32_bf16(
                    af[mi], bf[ni], acc[mi][ni], 0, 0, 0);
    }

    const int cn  = lane & 15;
    const int cr4 = (lane >> 4) * 4;
#pragma unroll
    for (int ni = 0; ni < 4; ++ni) {
        int col = bn * 128 + wn * 64 + ni * 16 + cn;
        float bv = bias[PERMBIAS ? invp_s(col) : col];
#pragma unroll
        for (int mi = 0; mi < 4; ++mi) {
            int row0 = bm * 128 + wm * 64 + mi * 16 + cr4;
#pragma unroll
            for (int q = 0; q < 4; ++q) {
                float v = acc[mi][ni][q] + bv;
                if (RELU) v = fmaxf(v, 0.f);
                if (TLAYOUT) {
                    // b = row0+q: g = b>>6 = bm*2+wm; bq = b&63 = mi*16+cr4+q
                    // f = col: i = col>>5, w = col&31
                    size_t addr = (size_t)(bm * 2 + wm) * ((size_t)N * 64)
                                + (size_t)(col >> 5) * 2048
                                + (size_t)(mi * 16 + cr4 + q) * 32 + (col & 31);
                    ((__bf16*)Cout)[addr] = (__bf16)v;
                } else if (OBF16) {
                    ((__bf16*)Cout)[(size_t)(row0 + q) * N + col] = (__bf16)v;
                } else {
                    ((float*)Cout)[(size_t)(row0 + q) * N + col] = v;
                }
            }
        }
    }
}

#define CFENCE() asm volatile("" ::: "memory")
#define BARX()  do { CFENCE(); __builtin_amdgcn_s_barrier(); CFENCE(); } while (0)
#define WVM2()  asm volatile("s_waitcnt vmcnt(2)" ::: "memory")
#define WVM0()  asm volatile("s_waitcnt vmcnt(0)" ::: "memory")
#define WLGK()  asm volatile("s_waitcnt lgkmcnt(0)" ::: "memory")

// ---------------------------------------------------------------------------
// gemm8p: 256x128 tile, 4-phase counted-vmcnt. Used for GEMM1/2 only
// (measured -22us combined vs gemm_bt in round 1; regressed G3 in round 1).
// No XCD swizzle (round 3: swizzle thrashes L3 on this L3-resident problem).
// ---------------------------------------------------------------------------
template <bool RELU, bool OBF16, bool TLAYOUT, bool PERMBIAS, int LMODE>
__global__ __launch_bounds__(512)
void gemm8p(const __bf16* __restrict__ A, const __bf16* __restrict__ Bw,
            const float* __restrict__ bias, void* __restrict__ Cout,
            int N, int K)
{
    __shared__ __align__(16) __bf16 ls[2 * 24576];
    const int tid  = threadIdx.x;
    const int wave = tid >> 6;
    const int lane = tid & 63;
    const int bm = blockIdx.x;
    const int bn = (gridDim.y - 1) - blockIdx.y;   // LPT order
    const int wm = wave >> 1, wn = wave & 1;       // 4M x 2N

    const int l8 = lane >> 3;
    const int cb = (lane & 7) ^ l8;
    const __bf16* gA[2][2];  int dA[2][2];
    const __bf16* gB[2];     int dB[2];
#pragma unroll
    for (int h = 0; h < 2; ++h)
#pragma unroll
        for (int s = 0; s < 2; ++s) {
            int rt = h * 128 + wave * 16 + s * 8;
            gA[h][s] = A + (size_t)(bm * 256 + rt + l8) * K + cb * 8;
            dA[h][s] = rt * 64;
        }
#pragma unroll
    for (int s = 0; s < 2; ++s) {
        int rt = wave * 16 + s * 8;
        gB[s] = Bw + (size_t)(bn * 128 + rt + l8) * K + cb * 8;
        dB[s] = 16384 + rt * 64;
    }

#define STG_A(buf, kt) do { \
    load_lds16((const void*)(gA[0][0] + (kt)), (void*)(ls + (buf)*24576 + dA[0][0])); \
    load_lds16((const void*)(gA[0][1] + (kt)), (void*)(ls + (buf)*24576 + dA[0][1])); \
    load_lds16((const void*)(gA[1][0] + (kt)), (void*)(ls + (buf)*24576 + dA[1][0])); \
    load_lds16((const void*)(gA[1][1] + (kt)), (void*)(ls + (buf)*24576 + dA[1][1])); } while (0)
#define STG_B(buf, kt) do { \
    load_lds16((const void*)(gB[0] + (kt)), (void*)(ls + (buf)*24576 + dB[0])); \
    load_lds16((const void*)(gB[1] + (kt)), (void*)(ls + (buf)*24576 + dB[1])); } while (0)

    const int fr  = lane & 15;
    const int ks  = lane >> 4;
    const int sx  = fr & 7;
    const int sl0 = ((ks)     ^ sx) * 8;
    const int sl1 = ((4 + ks) ^ sx) * 8;
    int aoff[4], boff[4];
#pragma unroll
    for (int i = 0; i < 4; ++i) {
        aoff[i] = (wm * 64 + i * 16 + fr) * 64;
        boff[i] = 16384 + (wn * 64 + i * 16 + fr) * 64;
    }

    floatx4 acc[4][4];
    const floatx4 vzero = {0.f, 0.f, 0.f, 0.f};
#pragma unroll
    for (int mi = 0; mi < 4; ++mi)
#pragma unroll
        for (int ni = 0; ni < 4; ++ni) acc[mi][ni] = vzero;

    bf16x8 bfr[4][2], afr[2][2];

#define DSRD_B(buf) do { \
    _Pragma("unroll") \
    for (int ni = 0; ni < 4; ++ni) { \
        bfr[ni][0] = *(const bf16x8*)(ls + (buf)*24576 + boff[ni] + sl0); \
        bfr[ni][1] = *(const bf16x8*)(ls + (buf)*24576 + boff[ni] + sl1); } } while (0)
#define DSRD_A(buf, q) do { \
    _Pragma("unroll") \
    for (int j = 0; j < 2; ++j) { \
        afr[j][0] = *(const bf16x8*)(ls + (buf)*24576 + aoff[2*(q)+j] + sl0); \
        afr[j][1] = *(const bf16x8*)(ls + (buf)*24576 + aoff[2*(q)+j] + sl1); } } while (0)
#define MFMA16(q) do { \
    __builtin_amdgcn_s_setprio(1); \
    _Pragma("unroll") \
    for (int j = 0; j < 2; ++j) \
    _Pragma("unroll") \
    for (int ni = 0; ni < 4; ++ni) { \
        acc[2*(q)+j][ni] = __builtin_amdgcn_mfma_f32_16x16x32_bf16( \
            afr[j][0], bfr[ni][0], acc[2*(q)+j][ni], 0, 0, 0); \
        acc[2*(q)+j][ni] = __builtin_amdgcn_mfma_f32_16x16x32_bf16( \
            afr[j][1], bfr[ni][1], acc[2*(q)+j][ni], 0, 0, 0); } \
    __builtin_amdgcn_s_setprio(0); } while (0)

    const int nk = K >> 6;
    int limit;
    if (LMODE == 0)      limit = (cnt_le(resp_s(bn * 128 + 127)) + 63) >> 6;
    else if (LMODE == 1) { int D = 4 * bn + 2; if (D > 126) D = 126;
                           limit = (cnt_le(D) + 63) >> 6; }
    else                 limit = (resp_s(bn * 128 + 127) + 64) >> 6;
    if (limit > nk) limit = nk;
    const int NT = limit;

    STG_B(0, 0);
    STG_A(0, 0);
    if (NT > 1) { STG_B(1, 64); WVM2(); } else { WVM0(); }
    BARX();

    for (int t = 0; ; t += 2) {
        const int kt1 = (t + 1) << 6, kt2 = (t + 2) << 6, kt3 = (t + 3) << 6;
        const bool has1 = t + 1 < NT, has2 = t + 2 < NT, has3 = t + 3 < NT;

        DSRD_B(0);
        DSRD_A(0, 0);
        if (has1) STG_A(1, kt1);
        BARX(); WLGK();
        MFMA16(0);
        BARX();

        DSRD_A(0, 1);
        if (has2) STG_B(0, kt2);
        BARX(); WLGK();
        MFMA16(1);
        if (!has1) break;
        if (has2) WVM2(); else WVM0();
        BARX();

        DSRD_B(1);
        DSRD_A(1, 0);
        if (has2) STG_A(0, kt2);
        BARX(); WLGK();
        MFMA16(0);
        BARX();

        DSRD_A(1, 1);
        if (has3) STG_B(1, kt3);
        BARX(); WLGK();
        MFMA16(1);
        if (!has2) break;
        if (has3) WVM2(); else WVM0();
        BARX();
    }

    const int cn  = lane & 15;
    const int cr4 = (lane >> 4) * 4;
#pragma unroll
    for (int ni = 0; ni < 4; ++ni) {
        int col = bn * 128 + wn * 64 + ni * 16 + cn;
        float bv = bias[PERMBIAS ? invp_s(col) : col];
#pragma unroll
        for (int mi = 0; mi < 4; ++mi) {
            int row0 = bm * 256 + wm * 64 + mi * 16 + cr4;
#pragma unroll
            for (int q = 0; q < 4; ++q) {
                float v = acc[mi][ni][q] + bv;
                if (RELU) v = fmaxf(v, 0.f);
                if (TLAYOUT) {
                    size_t addr = (size_t)(bm * 4 + wm) * ((size_t)N * 64)
                                + (size_t)(col >> 5) * 2048
                                + (size_t)(mi * 16 + cr4 + q) * 32 + (col & 31);
                    ((__bf16*)Cout)[addr] = (__bf16)v;
                } else if (OBF16) {
                    ((__bf16*)Cout)[(size_t)(row0 + q) * N + col] = (__bf16)v;
                } else {
                    ((float*)Cout)[(size_t)(row0 + q) * N + col] = v;
                }
            }
        }
    }
#undef STG_A
#undef STG_B
#undef DSRD_B
#undef DSRD_A
#undef MFMA16
}

// ---------------------------------------------------------------------------
// Fused log-semiring chain: 126 steps = 18 segs x 7 (round-7 change, isolated
// this round): 576 thr = 9 waves/block (+28% TLP vs 14x9), serial depth 7.
// Segments in registers -> LDS -> pair-tree fold + boundaries. theta layout
// th[b>>6][i][b&63][32]: step params contiguous 64B -> 4 bf16x8 loads/step.
// ---------------------------------------------------------------------------
__global__ __launch_bounds__(576)
void chain_all(const __bf16* __restrict__ th2,  // [128][128][64][32] bf16
               const float* __restrict__ x,     // [8192,128]
               float* __restrict__ out)         // [8192]
{
    __shared__ float xs[32 * 129];               // 16.5 KB (pad 129: no conflicts)
    __shared__ float Pl[32 * 306];               // 39.2 KB: [bl][s*17 + e], 18 segs
    const int tid = threadIdx.x;
    const int blk = blockIdx.x;                  // 0..255

    for (int idx = tid; idx < 4096; idx += 576) {
        int bl = idx >> 7, i = idx & 127;
        xs[bl * 129 + i] = x[(size_t)blk * 4096 + idx];
    }
    __syncthreads();

    const int s  = tid >> 5;                     // 0..17
    const int bl = tid & 31;
    const int b64 = (blk & 1) * 32 + bl;
    const __bf16* tb = th2 + (size_t)(blk >> 1) * 262144 + (size_t)b64 * 32;

    {   // segment product: 7 steps from i0
        const int i0 = 1 + s * 7;
        const __bf16* tp = tb + (size_t)i0 * 2048;
        float M[4][4];
#pragma unroll
        for (int r = 0; r < 4; ++r)
#pragma unroll
            for (int c = 0; c < 4; ++c) M[r][c] = (r == c) ? 0.f : -1e30f;

        for (int ii = 0; ii < 7; ++ii) {
            bf16x8 v0 = *(const bf16x8*)(tp);
            bf16x8 v1 = *(const bf16x8*)(tp + 8);
            bf16x8 v2 = *(const bf16x8*)(tp + 16);
            bf16x8 v3 = *(const bf16x8*)(tp + 24);
            float mu[16], al[16];
#pragma unroll
            for (int j = 0; j < 8; ++j) {
                mu[j] = (float)v0[j]; mu[8 + j] = (float)v1[j];
                al[j] = (float)v2[j]; al[8 + j] = (float)v3[j];
            }
            float xv = xs[bl * 129 + i0 + ii];
            tp += 2048;                          // next step
            float lp[16];
#pragma unroll
            for (int j = 0; j < 16; ++j) lp[j] = logp2(xv, mu[j], al[j]);
            float Mn[4][4];
#pragma unroll
            for (int r = 0; r < 4; ++r)
#pragma unroll
                for (int c = 0; c < 4; ++c)
                    Mn[r][c] = lse4(M[r][0] + lp[0 + c], M[r][1] + lp[4 + c],
                                    M[r][2] + lp[8 + c], M[r][3] + lp[12 + c]);
#pragma unroll
            for (int r = 0; r < 4; ++r)
#pragma unroll
                for (int c = 0; c < 4; ++c) M[r][c] = Mn[r][c];
        }
        float* pb = Pl + bl * 306 + s * 17;
#pragma unroll
        for (int r = 0; r < 4; ++r)
#pragma unroll
            for (int c = 0; c < 4; ++c) pb[r * 4 + c] = M[r][c];
    }
    __syncthreads();

    // fold level 1: 9 pair-products per batch (threads 0..287)
    float Q[16];
    if (tid < 288) {
        const float* base = Pl + bl * 306;
        lmm4(base + (2 * s) * 17, base + (2 * s + 1) * 17, Q);
    }
    __syncthreads();
    if (tid < 288) {
        float* dst = Pl + bl * 306 + s * 17;
#pragma unroll
        for (int e = 0; e < 16; ++e) dst[e] = Q[e];
    }
    __syncthreads();

    // fold level 2 + boundaries: one thread per batch (9 slots sequential)
    if (tid < 32) {
        const float* base = Pl + tid * 306;
        float M[16], T[16];
#pragma unroll
        for (int e = 0; e < 16; ++e) M[e] = base[e];
#pragma unroll
        for (int j = 1; j < 9; ++j) {
            lmm4(M, base + j * 17, T);
#pragma unroll
            for (int e = 0; e < 16; ++e) M[e] = T[e];
        }
        const int bb64 = (blk & 1) * 32 + tid;
        const __bf16* tbb = th2 + (size_t)(blk >> 1) * 262144 + (size_t)bb64 * 32;
        float x0 = xs[tid * 129 + 0];
        float xl = xs[tid * 129 + 127];
        float last[4], t4[4], f4[4];
        // last step i=127: mu at w=c*4 (a_row=c, a_col=0), al at 16+c*4
#pragma unroll
        for (int c = 0; c < 4; ++c)
            last[c] = logp2(xl, (float)tbb[(size_t)127 * 2048 + c * 4],
                                (float)tbb[(size_t)127 * 2048 + 16 + c * 4]);
#pragma unroll
        for (int r = 0; r < 4; ++r)
            t4[r] = lse4(M[r * 4 + 0] + last[0], M[r * 4 + 1] + last[1],
                         M[r * 4 + 2] + last[2], M[r * 4 + 3] + last[3]);
        // first step i=0: mu at w=r (a_row=0, a_col=r), al at 16+r
#pragma unroll
        for (int r = 0; r < 4; ++r)
            f4[r] = logp2(x0, (float)tbb[r], (float)tbb[16 + r]);
        out[blk * 32 + tid] = LN2 * lse4(f4[0] + t4[0], f4[1] + t4[1],
                                         f4[2] + t4[2], f4[3] + t4[3]);
    }
}

// ---------------------------------------------------------------------------
extern "C" void kernel_launch(void* const* d_in, const int* in_sizes, int n_in,
                              void* d_out, int out_size, void* d_ws, size_t ws_size,
                              hipStream_t stream)
{
    (void)in_sizes; (void)n_in; (void)out_size; (void)ws_size;
    const float* x  = (const float*)d_in[0];
    const float* W0 = (const float*)d_in[1];
    const float* b0 = (const float*)d_in[2];
    const float* W1 = (const float*)d_in[3];
    const float* b1 = (const float*)d_in[4];
    const float* W2 = (const float*)d_in[5];
    const float* b2 = (const float*)d_in[6];
    const float* W3 = (const float*)d_in[7];
    const float* b3 = (const float*)d_in[8];

    // Compact arena (112 MB): th overlays regions dead before GEMM3.
    char* ws = (char*)d_ws;
    const size_t MB = 1024 * 1024;
    __bf16* h2  = (__bf16*)(ws + 0);          // 32 MB: g1 out, g2 in; dead after g2
    __bf16* xb  = (__bf16*)(ws + 32 * MB);    // 2 MB:  prep -> g0
    __bf16* w0m = (__bf16*)(ws + 34 * MB);    // 0.5MB: prep -> g0
    __bf16* w1m = (__bf16*)(ws + 35 * MB);    // 8 MB:  prep -> g1
    __bf16* w2m = (__bf16*)(ws + 43 * MB);    // 8 MB:  prep -> g2
    __bf16* th  = (__bf16*)(ws + 0);          // 64 MB: g3 out (overlays the above)
    __bf16* w3m = (__bf16*)(ws + 64 * MB);    // 16 MB: prep -> g3 (not overlaid)
    __bf16* h1  = (__bf16*)(ws + 80 * MB);    // 32 MB: g0 out; g2 writes h3=h1; g3 in
    __bf16* h3  = h1;

    prep_all<<<8832, 256, 0, stream>>>(x, W0, W1, W2, W3, xb, w0m, w1m, w2m, w3m);

    // GEMM0: sorted N, natural K=128 (LMODE 2) — LDS-staged 128^2 kernel
    // (r7 lesson: LDS-free variant causes 9x write amplification)
    gemm_bt<true, true, false, true, 2><<<dim3(64, 16), 256, 0, stream>>>(
        xb, w0m, b0, h1, 2048, 128);
    // GEMM1/2: sorted N, sorted K (LMODE 0) — 256x128 4-phase (round-1 best)
    gemm8p<true, true, false, true, 0><<<dim3(32, 16), 512, 0, stream>>>(
        h1, w1m, b1, h2, 2048, 2048);
    gemm8p<true, true, false, true, 0><<<dim3(32, 16), 512, 0, stream>>>(
        h2, w2m, b2, h3, 2048, 2048);
    // GEMM3: natural N, sorted K (LMODE 1) — 128^2 kernel (round-0 best),
    // theta stored step-contiguous for chain
    gemm_bt<false, false, true, false, 1><<<dim3(64, 32), 256, 0, stream>>>(
        h3, w3m, b3, th, 4096, 2048);

    // fused segment chain + fold (single dispatch)
    chain_all<<<256, 576, 0, stream>>>(th, x, (float*)d_out);
}